// Round 4
// baseline (5071.234 us; speedup 1.0000x reference)
//
#include <hip/hip_runtime.h>
#include <cstdint>

#define BATCH 64
#define SEQ   1024
#define FEAT  16
#define HID   256
#define GATE  768   // 3*HID
#define TC    128   // time-chunk length
#define TCSH  7     // log2(TC)
#define NT    512   // gru block threads (8 waves)

typedef _Float16 h2 __attribute__((ext_vector_type(2)));

__device__ __forceinline__ float dot2f(float a, float b, float c) {
    return __builtin_amdgcn_fdot2(__builtin_bit_cast(h2, a),
                                  __builtin_bit_cast(h2, b), c, false);
}
__device__ __forceinline__ float sigmoidf_(float x) { return 1.0f / (1.0f + __expf(-x)); }
__device__ __forceinline__ float tanhf_(float x)    { return 2.0f / (1.0f + __expf(-2.0f * x)) - 1.0f; }

// ---------------------------------------------------------------------------
// Pack U (fp32 [HID][GATE]) -> Upk (f16x2 dwords, [GATE][HID/2]):
// Upk[c][kk] = (half(U[2kk][c]), half(U[2kk+1][c]))
// ---------------------------------------------------------------------------
__global__ __launch_bounds__(256) void k_packU(const float* __restrict__ U,
                                               float* __restrict__ Upk)
{
    const int idx = blockIdx.x * 256 + threadIdx.x;   // < GATE * 128
    const int c  = idx >> 7;
    const int kk = idx & 127;
    h2 v;
    v.x = (_Float16)U[(size_t)(2 * kk)     * GATE + c];
    v.y = (_Float16)U[(size_t)(2 * kk + 1) * GATE + c];
    Upk[idx] = __builtin_bit_cast(float, v);
}

// ---------------------------------------------------------------------------
// Layer-0 input projection
// ---------------------------------------------------------------------------
__global__ __launch_bounds__(256) void k_xp0(
    const int* __restrict__ batch, const float* __restrict__ W0,
    const float* __restrict__ b0, float* __restrict__ xp, int t0)
{
    const int r   = blockIdx.x;                       // 0 .. BATCH*TC-1
    const int col = blockIdx.y * 256 + threadIdx.x;   // 0 .. GATE-1
    const int b   = r >> TCSH;
    const int tl  = r & (TC - 1);
    const int* x = batch + ((size_t)b * SEQ + t0 + tl) * FEAT;
    float acc = b0[col];
#pragma unroll
    for (int f = 0; f < FEAT; ++f)
        acc += (float)x[f] * W0[f * GATE + col];
    xp[(size_t)r * GATE + col] = acc;
}

// ---------------------------------------------------------------------------
// Layers 1/2 input projection GEMM (64x128 tile, K-step 16)
// ---------------------------------------------------------------------------
#define BM 64
#define BN 128
#define BK 16

__global__ __launch_bounds__(256) void k_gemm(
    const float* __restrict__ Y, const float* __restrict__ W,
    const float* __restrict__ b0, float* __restrict__ xp, int t0)
{
    __shared__ float As[BK][BM + 4];
    __shared__ float Bs[BK][BN];

    const int m0 = blockIdx.x * BM;
    const int n0 = blockIdx.y * BN;
    const int tid = threadIdx.x;
    const int tx = tid & 31;
    const int ty = tid >> 5;
    const int ar = tid >> 2;
    const int ac = (tid & 3) * 4;
    const int kr = tid >> 4;
    const int bc = (tid & 15) * 8;

    float acc[8][4] = {};

    for (int k0 = 0; k0 < HID; k0 += BK) {
        {
            const int r  = m0 + ar;
            const int b  = r >> TCSH;
            const int tl = r & (TC - 1);
            float4 av = *(const float4*)(Y + ((size_t)b * SEQ + t0 + tl) * HID + k0 + ac);
            As[ac + 0][ar] = av.x; As[ac + 1][ar] = av.y;
            As[ac + 2][ar] = av.z; As[ac + 3][ar] = av.w;
            float4 bv0 = *(const float4*)(W + (size_t)(k0 + kr) * GATE + n0 + bc);
            float4 bv1 = *(const float4*)(W + (size_t)(k0 + kr) * GATE + n0 + bc + 4);
            *(float4*)&Bs[kr][bc]     = bv0;
            *(float4*)&Bs[kr][bc + 4] = bv1;
        }
        __syncthreads();
#pragma unroll
        for (int k = 0; k < BK; ++k) {
            float4 a0 = *(const float4*)&As[k][ty * 8];
            float4 a1 = *(const float4*)&As[k][ty * 8 + 4];
            float4 bv = *(const float4*)&Bs[k][tx * 4];
            float av_[8] = {a0.x, a0.y, a0.z, a0.w, a1.x, a1.y, a1.z, a1.w};
            float bv_[4] = {bv.x, bv.y, bv.z, bv.w};
#pragma unroll
            for (int i = 0; i < 8; ++i)
#pragma unroll
                for (int j = 0; j < 4; ++j)
                    acc[i][j] += av_[i] * bv_[j];
        }
        __syncthreads();
    }

#pragma unroll
    for (int i = 0; i < 8; ++i) {
        const int r = m0 + ty * 8 + i;
        float* crow = xp + (size_t)r * GATE + n0 + tx * 4;
#pragma unroll
        for (int j = 0; j < 4; ++j)
            crow[j] = acc[i][j] + b0[n0 + tx * 4 + j];
    }
}

// ---------------------------------------------------------------------------
// GRU recurrence v3: wave-local gates, 1 barrier/step, double-buffered h,
// 1-step xp/mask prefetch.
// 512 threads (8 waves). Wave w owns h-cols [32w,32w+32). Lane l: quad
// q=l>>2 owns h-cols {c0,c0+1} (c0=32w+2q); sub=l&3 is the k-quarter.
// U fragment/lane: 6 U-cols (z0,z1,r0,r1,h0,h1) x 32 dwords = 192 VGPRs.
// Intra-quad butterfly (shfl_xor 1,2 -> DPP) gives every lane full sums;
// lane computes gates for col cg=c0+(sub&1); sub<2 lanes store.
// h f16-packed in 2 LDS buffers of 4x144B swizzled chunks (conflict-free).
// ---------------------------------------------------------------------------
__global__ __launch_bounds__(NT, 2) void k_gru(
    const float* __restrict__ xp, const float* __restrict__ Upk,
    const float* __restrict__ b1, const int* __restrict__ batch,
    float* __restrict__ out, float* __restrict__ hfinal,
    float* __restrict__ hstate, int t0)
{
    __shared__ __align__(16) char hbuf[2][4 * 144];

    const int b   = blockIdx.x;
    const int T   = threadIdx.x;
    const int w   = T >> 6;
    const int l   = T & 63;
    const int sub = l & 3;          // k-quarter
    const int q   = l >> 2;         // 0..15
    const int c0  = w * 32 + 2 * q; // first of this quad's 2 h-cols
    const int cg  = c0 + (sub & 1); // this lane's gate column

    // ---- load U fragment: 6 cols x 32 dwords ----
    float u[6][32];
    {
        const int cols[6] = {c0, c0 + 1, HID + c0, HID + c0 + 1,
                             2 * HID + c0, 2 * HID + c0 + 1};
#pragma unroll
        for (int ci = 0; ci < 6; ++ci) {
            const float4* src = (const float4*)(Upk + (size_t)cols[ci] * 128 + sub * 32);
#pragma unroll
            for (int i = 0; i < 8; ++i) {
                float4 v = src[i];
                u[ci][4 * i + 0] = v.x; u[ci][4 * i + 1] = v.y;
                u[ci][4 * i + 2] = v.z; u[ci][4 * i + 3] = v.w;
            }
        }
    }

    const float bz = b1[cg];
    const float br = b1[HID + cg];
    const float bh = b1[2 * HID + cg];

    // ---- init h (all lanes track hprev for their gate col) ----
    float hprev = (t0 == 0) ? 0.0f : hstate[b * HID + cg];
    if (sub < 2) {
        const int Q = cg >> 6, d = cg & 63;
        *(_Float16*)(&hbuf[0][0] + Q * 144 + (d >> 1) * 4 + (d & 1) * 2) = (_Float16)hprev;
    }

    // ---- prefetch xp/mask for step 0 ----
    float cxz, cxr, cxh; int cmf;
    {
        const float* xrow = xp + ((size_t)b * TC + 0) * GATE;
        cxz = xrow[cg]; cxr = xrow[HID + cg]; cxh = xrow[2 * HID + cg];
        cmf = batch[((size_t)b * SEQ + t0) * FEAT + (FEAT - 1)];
    }
    __syncthreads();

    for (int tl = 0; tl < TC; ++tl) {
        const char* rd = &hbuf[tl & 1][0];
        char*       wr = &hbuf[(tl & 1) ^ 1][0];

        // issue prefetch for next step (consumed next iteration)
        float nxz, nxr, nxh; int nmf;
        {
            const int tln = (tl + 1 < TC) ? tl + 1 : tl;
            const float* xrow = xp + ((size_t)b * TC + tln) * GATE;
            nxz = xrow[cg]; nxr = xrow[HID + cg]; nxh = xrow[2 * HID + cg];
            nmf = batch[((size_t)b * SEQ + t0 + tln) * FEAT + (FEAT - 1)];
        }

        // ---- matvec partials over this lane's k-quarter ----
        const float4* h4 = (const float4*)(rd + sub * 144);
        float a0 = 0.f, a1 = 0.f, a2 = 0.f, a3 = 0.f, a4 = 0.f, a5 = 0.f;
#pragma unroll
        for (int i = 0; i < 8; ++i) {
            float4 hv = h4[i];
            a0 = dot2f(hv.x, u[0][4 * i + 0], a0);
            a0 = dot2f(hv.y, u[0][4 * i + 1], a0);
            a0 = dot2f(hv.z, u[0][4 * i + 2], a0);
            a0 = dot2f(hv.w, u[0][4 * i + 3], a0);
            a1 = dot2f(hv.x, u[1][4 * i + 0], a1);
            a1 = dot2f(hv.y, u[1][4 * i + 1], a1);
            a1 = dot2f(hv.z, u[1][4 * i + 2], a1);
            a1 = dot2f(hv.w, u[1][4 * i + 3], a1);
            a2 = dot2f(hv.x, u[2][4 * i + 0], a2);
            a2 = dot2f(hv.y, u[2][4 * i + 1], a2);
            a2 = dot2f(hv.z, u[2][4 * i + 2], a2);
            a2 = dot2f(hv.w, u[2][4 * i + 3], a2);
            a3 = dot2f(hv.x, u[3][4 * i + 0], a3);
            a3 = dot2f(hv.y, u[3][4 * i + 1], a3);
            a3 = dot2f(hv.z, u[3][4 * i + 2], a3);
            a3 = dot2f(hv.w, u[3][4 * i + 3], a3);
            a4 = dot2f(hv.x, u[4][4 * i + 0], a4);
            a4 = dot2f(hv.y, u[4][4 * i + 1], a4);
            a4 = dot2f(hv.z, u[4][4 * i + 2], a4);
            a4 = dot2f(hv.w, u[4][4 * i + 3], a4);
            a5 = dot2f(hv.x, u[5][4 * i + 0], a5);
            a5 = dot2f(hv.y, u[5][4 * i + 1], a5);
            a5 = dot2f(hv.z, u[5][4 * i + 2], a5);
            a5 = dot2f(hv.w, u[5][4 * i + 3], a5);
        }

        // ---- intra-quad butterfly: all 4 lanes get full sums ----
        a0 += __shfl_xor(a0, 1, 64); a0 += __shfl_xor(a0, 2, 64);
        a1 += __shfl_xor(a1, 1, 64); a1 += __shfl_xor(a1, 2, 64);
        a2 += __shfl_xor(a2, 1, 64); a2 += __shfl_xor(a2, 2, 64);
        a3 += __shfl_xor(a3, 1, 64); a3 += __shfl_xor(a3, 2, 64);
        a4 += __shfl_xor(a4, 1, 64); a4 += __shfl_xor(a4, 2, 64);
        a5 += __shfl_xor(a5, 1, 64); a5 += __shfl_xor(a5, 2, 64);

        // ---- wave-local gates for col cg ----
        {
            const int s = sub & 1;
            const float az = s ? a1 : a0;
            const float ar = s ? a3 : a2;
            const float ah = s ? a5 : a4;
            const float z  = sigmoidf_(cxz + az + bz);
            const float r  = sigmoidf_(cxr + ar + br);
            const float hh = tanhf_(cxh + r * (ah + bh));
            float hn = z * hprev + (1.0f - z) * hh;
            hn = (cmf != -1) ? hn : hprev;
            hprev = hn;
            if (sub < 2) {
                out[((size_t)b * SEQ + t0 + tl) * HID + cg] = hn;
                const int Q = cg >> 6, d = cg & 63;
                *(_Float16*)(wr + Q * 144 + (d >> 1) * 4 + (d & 1) * 2) = (_Float16)hn;
            }
        }

        cxz = nxz; cxr = nxr; cxh = nxh; cmf = nmf;
        __syncthreads();
    }

    if (sub < 2) {
        hstate[b * HID + cg] = hprev;
        if (hfinal) hfinal[b * HID + cg] = hprev;
    }
}

// ---------------------------------------------------------------------------
extern "C" void kernel_launch(void* const* d_in, const int* in_sizes, int n_in,
                              void* d_out, int out_size, void* d_ws, size_t ws_size,
                              hipStream_t stream)
{
    const int*   batch = (const int*)d_in[0];
    const float* W0 = (const float*)d_in[1];
    const float* U0 = (const float*)d_in[2];
    const float* b0 = (const float*)d_in[3];
    const float* W1 = (const float*)d_in[4];
    const float* U1 = (const float*)d_in[5];
    const float* b1 = (const float*)d_in[6];
    const float* W2 = (const float*)d_in[7];
    const float* U2 = (const float*)d_in[8];
    const float* b2 = (const float*)d_in[9];

    float* out  = (float*)d_out;
    float* hfin = out + (size_t)BATCH * SEQ * HID;

    // ws layout: xp chunk | y | hstate | Upk0 | Upk1 | Upk2
    float* xp     = (float*)d_ws;
    float* y      = xp + (size_t)BATCH * TC * GATE;
    float* hstate = y + (size_t)BATCH * SEQ * HID;
    float* Upk0   = hstate + (size_t)BATCH * HID;
    float* Upk1   = Upk0 + (size_t)GATE * 128;
    float* Upk2   = Upk1 + (size_t)GATE * 128;

    dim3 gpack(GATE * 128 / 256), bpack(256);
    dim3 gxp0(BATCH * TC, 3), bxp0(256);
    dim3 ggemm(BATCH * TC / BM, GATE / BN), bgemm(256);
    dim3 ggru(BATCH), bgru(NT);

    k_packU<<<gpack, bpack, 0, stream>>>(U0, Upk0);
    k_packU<<<gpack, bpack, 0, stream>>>(U1, Upk1);
    k_packU<<<gpack, bpack, 0, stream>>>(U2, Upk2);

    // ----- layer 0 -----
    for (int t0 = 0; t0 < SEQ; t0 += TC) {
        k_xp0<<<gxp0, bxp0, 0, stream>>>(batch, W0, b0, xp, t0);
        k_gru<<<ggru, bgru, 0, stream>>>(xp, Upk0, b0 + GATE, batch, y, nullptr, hstate, t0);
    }
    // ----- layer 1 -----
    for (int t0 = 0; t0 < SEQ; t0 += TC) {
        k_gemm<<<ggemm, bgemm, 0, stream>>>(y, W1, b1, xp, t0);
        k_gru<<<ggru, bgru, 0, stream>>>(xp, Upk1, b1 + GATE, batch, y, nullptr, hstate, t0);
    }
    // ----- layer 2 -----
    for (int t0 = 0; t0 < SEQ; t0 += TC) {
        k_gemm<<<ggemm, bgemm, 0, stream>>>(y, W2, b2, xp, t0);
        k_gru<<<ggru, bgru, 0, stream>>>(xp, Upk2, b2 + GATE, batch, out,
                                         (t0 + TC == SEQ) ? hfin : nullptr, hstate, t0);
    }
}

// Round 5
// 4760.531 us; speedup vs baseline: 1.0653x; 1.0653x over previous
//
#include <hip/hip_runtime.h>
#include <cstdint>

#define BATCH 64
#define SEQ   1024
#define FEAT  16
#define HID   256
#define GATE  768   // 3*HID
#define TC    128   // time-chunk length
#define TCSH  7     // log2(TC)
#define NT    512   // gru block threads (8 waves)

typedef _Float16 f16x8 __attribute__((ext_vector_type(8)));
typedef float    f32x4 __attribute__((ext_vector_type(4)));

__device__ __forceinline__ float sigmoidf_(float x) { return 1.0f / (1.0f + __expf(-x)); }
__device__ __forceinline__ float tanhf_(float x)    { return 2.0f / (1.0f + __expf(-2.0f * x)) - 1.0f; }

// ---------------------------------------------------------------------------
// Pack U (fp32 [HID][GATE]) into MFMA B-fragments (f16), register-load-ready.
// Fragment (ct, kt, lane) holds 8 f16: U[kt*32 + (lane>>4)*8 + e][ct*16 + (lane&15)]
// stored at Bfrag[((ct*8 + kt)*64 + lane) * 4] (4 dwords = 8 f16).
// Same k-slot mapping is used for the A side, so any HW k-permutation cancels.
// ---------------------------------------------------------------------------
__global__ __launch_bounds__(256) void k_packB(const float* __restrict__ U,
                                               float* __restrict__ Bfrag)
{
    const int tid = blockIdx.x * 256 + threadIdx.x;   // < 48*8*64
    const int ct   = tid >> 9;
    const int kt   = (tid >> 6) & 7;
    const int lane = tid & 63;
    const int g = lane >> 4, i = lane & 15;
    const int col = ct * 16 + i;
    const int k0  = kt * 32 + g * 8;
    union { f16x8 v; float4 f; } u;
#pragma unroll
    for (int e = 0; e < 8; ++e)
        u.v[e] = (_Float16)U[(size_t)(k0 + e) * GATE + col];
    *(float4*)(Bfrag + (size_t)tid * 4) = u.f;
}

// ---------------------------------------------------------------------------
// Layer-0 input projection. Adds input bias b[0] and (for z,r cols) the
// recurrent bias b[1] (valid because z,r biases are additive pre-activation).
// ---------------------------------------------------------------------------
__global__ __launch_bounds__(256) void k_xp0(
    const int* __restrict__ batch, const float* __restrict__ W0,
    const float* __restrict__ bb, float* __restrict__ xp, int t0)
{
    const int r   = blockIdx.x;                       // 0 .. BATCH*TC-1
    const int col = blockIdx.y * 256 + threadIdx.x;   // 0 .. GATE-1
    const int b   = r >> TCSH;
    const int tl  = r & (TC - 1);
    const int* x = batch + ((size_t)b * SEQ + t0 + tl) * FEAT;
    float acc = bb[col] + ((col < 2 * HID) ? bb[GATE + col] : 0.0f);
#pragma unroll
    for (int f = 0; f < FEAT; ++f)
        acc += (float)x[f] * W0[f * GATE + col];
    xp[(size_t)r * GATE + col] = acc;
}

// ---------------------------------------------------------------------------
// Layers 1/2 input projection GEMM (64x128 tile, K-step 16). Bias as above.
// ---------------------------------------------------------------------------
#define BM 64
#define BN 128
#define BK 16

__global__ __launch_bounds__(256) void k_gemm(
    const float* __restrict__ Y, const float* __restrict__ W,
    const float* __restrict__ bb, float* __restrict__ xp, int t0)
{
    __shared__ float As[BK][BM + 4];
    __shared__ float Bs[BK][BN];

    const int m0 = blockIdx.x * BM;
    const int n0 = blockIdx.y * BN;
    const int tid = threadIdx.x;
    const int tx = tid & 31;
    const int ty = tid >> 5;
    const int ar = tid >> 2;
    const int ac = (tid & 3) * 4;
    const int kr = tid >> 4;
    const int bc = (tid & 15) * 8;

    float acc[8][4] = {};

    for (int k0 = 0; k0 < HID; k0 += BK) {
        {
            const int r  = m0 + ar;
            const int b  = r >> TCSH;
            const int tl = r & (TC - 1);
            float4 av = *(const float4*)(Y + ((size_t)b * SEQ + t0 + tl) * HID + k0 + ac);
            As[ac + 0][ar] = av.x; As[ac + 1][ar] = av.y;
            As[ac + 2][ar] = av.z; As[ac + 3][ar] = av.w;
            float4 bv0 = *(const float4*)(W + (size_t)(k0 + kr) * GATE + n0 + bc);
            float4 bv1 = *(const float4*)(W + (size_t)(k0 + kr) * GATE + n0 + bc + 4);
            *(float4*)&Bs[kr][bc]     = bv0;
            *(float4*)&Bs[kr][bc + 4] = bv1;
        }
        __syncthreads();
#pragma unroll
        for (int k = 0; k < BK; ++k) {
            float4 a0 = *(const float4*)&As[k][ty * 8];
            float4 a1 = *(const float4*)&As[k][ty * 8 + 4];
            float4 bv = *(const float4*)&Bs[k][tx * 4];
            float av_[8] = {a0.x, a0.y, a0.z, a0.w, a1.x, a1.y, a1.z, a1.w};
            float bv_[4] = {bv.x, bv.y, bv.z, bv.w};
#pragma unroll
            for (int i = 0; i < 8; ++i)
#pragma unroll
                for (int j = 0; j < 4; ++j)
                    acc[i][j] += av_[i] * bv_[j];
        }
        __syncthreads();
    }

#pragma unroll
    for (int i = 0; i < 8; ++i) {
        const int r = m0 + ty * 8 + i;
        float* crow = xp + (size_t)r * GATE + n0 + tx * 4;
#pragma unroll
        for (int j = 0; j < 4; ++j) {
            const int n = n0 + tx * 4 + j;
            crow[j] = acc[i][j] + bb[n] + ((n < 2 * HID) ? bb[GATE + n] : 0.0f);
        }
    }
}

// ---------------------------------------------------------------------------
// GRU recurrence v4 (MFMA): 512 threads, 8 waves, wave w owns h-cols
// [32w, 32w+32). Matvec rec = h @ U done with mfma_f32_16x16x32_f16 with
// h broadcast into all 16 A-rows (1 ds_read_b128 per k-tile per lane) and U
// register-resident as 6 col-tiles x 8 k-tiles of B-fragments (192 VGPRs).
// All C rows equal -> no reduction; lane (g=l>>4, i=l&15) owns gate column
// c = 32w + i + 16*(g&1) (row-groups 2,3 duplicate). 1 barrier/step,
// double-buffered f16 h in LDS.
// ---------------------------------------------------------------------------
__global__ __launch_bounds__(NT, 1) void k_gru(
    const float* __restrict__ xp, const float* __restrict__ Bfrag,
    const float* __restrict__ bb, const int* __restrict__ batch,
    float* __restrict__ out, float* __restrict__ hfinal,
    float* __restrict__ hstate, int t0)
{
    __shared__ __align__(16) _Float16 hbuf[2][HID];

    const int b  = blockIdx.x;
    const int T  = threadIdx.x;
    const int w  = T >> 6;
    const int l  = T & 63;
    const int g  = l >> 4;
    const int i  = l & 15;
    const int g1 = g & 1;
    const int c  = 32 * w + i + 16 * g1;   // this lane's gate/h column

    // ---- load register-resident B fragments: 6 col-tiles x 8 k-tiles ----
    // col-tile order: [z|z+1]? -> group A (g1=0): z,r,h tiles 2w,16+2w,32+2w;
    // group B (g1=1): 2w+1, 17+2w, 33+2w.
    f16x8 Bf[6][8];
    {
        const int cts[6] = {2 * w, 16 + 2 * w, 32 + 2 * w,
                            2 * w + 1, 17 + 2 * w, 33 + 2 * w};
#pragma unroll
        for (int ci = 0; ci < 6; ++ci) {
#pragma unroll
            for (int kt = 0; kt < 8; ++kt) {
                float4 v = *(const float4*)(Bfrag + ((size_t)(cts[ci] * 8 + kt) * 64 + l) * 4);
                Bf[ci][kt] = __builtin_bit_cast(f16x8, v);
            }
        }
    }

    const float bh = bb[GATE + 2 * HID + c];   // recurrent bias, h gate only

    // ---- init h ----
    float hprev = (t0 == 0) ? 0.0f : hstate[b * HID + c];
    if (l < 32) hbuf[0][32 * w + l] = (_Float16)hprev;   // c == 32w+l here
    __syncthreads();

    for (int tl = 0; tl < TC; ++tl) {
        // xp/mask loads issued up front; consumed after the mfma chain (~L2 hidden)
        const float* xrow = xp + ((size_t)b * TC + tl) * GATE;
        const float xz = xrow[c];
        const float xr = xrow[HID + c];
        const float xh = xrow[2 * HID + c];
        const int   mf = batch[((size_t)b * SEQ + t0 + tl) * FEAT + (FEAT - 1)];

        const _Float16* rd = hbuf[tl & 1];

        f32x4 az0 = {0.f, 0.f, 0.f, 0.f}, ar0 = az0, ah0 = az0;
        f32x4 az1 = az0, ar1 = az0, ah1 = az0;
#pragma unroll
        for (int kt = 0; kt < 8; ++kt) {
            const f16x8 a = *(const f16x8*)(rd + kt * 32 + g * 8);  // ds_read_b128, 16-lane broadcast
            az0 = __builtin_amdgcn_mfma_f32_16x16x32_f16(a, Bf[0][kt], az0, 0, 0, 0);
            ar0 = __builtin_amdgcn_mfma_f32_16x16x32_f16(a, Bf[1][kt], ar0, 0, 0, 0);
            ah0 = __builtin_amdgcn_mfma_f32_16x16x32_f16(a, Bf[2][kt], ah0, 0, 0, 0);
            az1 = __builtin_amdgcn_mfma_f32_16x16x32_f16(a, Bf[3][kt], az1, 0, 0, 0);
            ar1 = __builtin_amdgcn_mfma_f32_16x16x32_f16(a, Bf[4][kt], ar1, 0, 0, 0);
            ah1 = __builtin_amdgcn_mfma_f32_16x16x32_f16(a, Bf[5][kt], ah1, 0, 0, 0);
        }

        // all C rows equal (broadcast A): take element 0; select group by g1
        const float az = g1 ? az1[0] : az0[0];
        const float ar = g1 ? ar1[0] : ar0[0];
        const float ah = g1 ? ah1[0] : ah0[0];

        // ---- gates (z,r biases pre-folded into xp) ----
        const float z  = sigmoidf_(xz + az);
        const float r  = sigmoidf_(xr + ar);
        const float hh = tanhf_(xh + r * (ah + bh));
        float hn = z * hprev + (1.0f - z) * hh;
        hn = (mf != -1) ? hn : hprev;
        hprev = hn;

        if (l < 32) {
            out[((size_t)b * SEQ + t0 + tl) * HID + 32 * w + l] = hn;
            hbuf[(tl & 1) ^ 1][32 * w + l] = (_Float16)hn;
        }
        __syncthreads();
    }

    if (l < 32) {
        hstate[b * HID + 32 * w + l] = hprev;
        if (hfinal) hfinal[b * HID + 32 * w + l] = hprev;
    }
}

// ---------------------------------------------------------------------------
extern "C" void kernel_launch(void* const* d_in, const int* in_sizes, int n_in,
                              void* d_out, int out_size, void* d_ws, size_t ws_size,
                              hipStream_t stream)
{
    const int*   batch = (const int*)d_in[0];
    const float* W0 = (const float*)d_in[1];
    const float* U0 = (const float*)d_in[2];
    const float* b0 = (const float*)d_in[3];
    const float* W1 = (const float*)d_in[4];
    const float* U1 = (const float*)d_in[5];
    const float* b1 = (const float*)d_in[6];
    const float* W2 = (const float*)d_in[7];
    const float* U2 = (const float*)d_in[8];
    const float* b2 = (const float*)d_in[9];

    float* out  = (float*)d_out;
    float* hfin = out + (size_t)BATCH * SEQ * HID;

    // ws layout: xp chunk | y | hstate | Bf0 | Bf1 | Bf2
    float* xp     = (float*)d_ws;
    float* y      = xp + (size_t)BATCH * TC * GATE;
    float* hstate = y + (size_t)BATCH * SEQ * HID;
    float* Bf0    = hstate + (size_t)BATCH * HID;
    float* Bf1    = Bf0 + (size_t)48 * 8 * 64 * 4;
    float* Bf2    = Bf1 + (size_t)48 * 8 * 64 * 4;

    dim3 gpack(48 * 8 * 64 / 256), bpack(256);
    dim3 gxp0(BATCH * TC, 3), bxp0(256);
    dim3 ggemm(BATCH * TC / BM, GATE / BN), bgemm(256);
    dim3 ggru(BATCH), bgru(NT);

    k_packB<<<gpack, bpack, 0, stream>>>(U0, Bf0);
    k_packB<<<gpack, bpack, 0, stream>>>(U1, Bf1);
    k_packB<<<gpack, bpack, 0, stream>>>(U2, Bf2);

    // ----- layer 0 -----
    for (int t0 = 0; t0 < SEQ; t0 += TC) {
        k_xp0<<<gxp0, bxp0, 0, stream>>>(batch, W0, b0, xp, t0);
        k_gru<<<ggru, bgru, 0, stream>>>(xp, Bf0, b0, batch, y, nullptr, hstate, t0);
    }
    // ----- layer 1 -----
    for (int t0 = 0; t0 < SEQ; t0 += TC) {
        k_gemm<<<ggemm, bgemm, 0, stream>>>(y, W1, b1, xp, t0);
        k_gru<<<ggru, bgru, 0, stream>>>(xp, Bf1, b1, batch, y, nullptr, hstate, t0);
    }
    // ----- layer 2 -----
    for (int t0 = 0; t0 < SEQ; t0 += TC) {
        k_gemm<<<ggemm, bgemm, 0, stream>>>(y, W2, b2, xp, t0);
        k_gru<<<ggru, bgru, 0, stream>>>(xp, Bf2, b2, batch, out,
                                         (t0 + TC == SEQ) ? hfin : nullptr, hstate, t0);
    }
}

// Round 6
// 2531.562 us; speedup vs baseline: 2.0032x; 1.8805x over previous
//
#include <hip/hip_runtime.h>
#include <cstdint>

#define BATCH 64
#define SEQ   1024
#define FEAT  16
#define HID   256
#define GATE  768    // 3*HID
#define TC    64     // time-chunk length
#define LASTC 15     // SEQ/TC - 1
#define NT    512    // fused-kernel block threads (8 waves)

typedef _Float16 f16x8 __attribute__((ext_vector_type(8)));
typedef float    f32x4 __attribute__((ext_vector_type(4)));

__device__ __forceinline__ float sigmoidf_(float x) { return 1.0f / (1.0f + __expf(-x)); }
__device__ __forceinline__ float tanhf_(float x)    { return 2.0f / (1.0f + __expf(-2.0f * x)) - 1.0f; }

// ---------------------------------------------------------------------------
// Pack U (fp32 [HID][GATE]) into MFMA B-fragments (f16).
// Fragment (ct, kt, lane): 8 f16 = U[kt*32 + (lane>>4)*8 + e][ct*16 + (lane&15)]
// at Bfrag[((ct*8 + kt)*64 + lane) * 4].
// ---------------------------------------------------------------------------
__global__ __launch_bounds__(256) void k_packB(const float* __restrict__ U,
                                               float* __restrict__ Bfrag)
{
    const int tid = blockIdx.x * 256 + threadIdx.x;   // < 48*8*64
    const int ct   = tid >> 9;
    const int kt   = (tid >> 6) & 7;
    const int lane = tid & 63;
    const int g = lane >> 4, i = lane & 15;
    const int col = ct * 16 + i;
    const int k0  = kt * 32 + g * 8;
    union { f16x8 v; float4 f; } u;
#pragma unroll
    for (int e = 0; e < 8; ++e)
        u.v[e] = (_Float16)U[(size_t)(k0 + e) * GATE + col];
    *(float4*)(Bfrag + (size_t)tid * 4) = u.f;
}

// ---------------------------------------------------------------------------
// Parameter block for the fused pipeline kernel
// ---------------------------------------------------------------------------
struct Params {
    const int*   batch;
    const float *W0, *b0, *W1, *b1, *W2, *b2;
    const float *Bf0, *Bf1, *Bf2;
    float *xp0a, *xp0b, *xp1a, *xp1b, *xp2a, *xp2b;   // xp rings (chunk-local)
    float *y0a, *y0b, *y1a, *y1b;                     // y rings (chunk-local)
    float *h0, *h1, *h2;                              // per-layer h state
    float *out, *hfin;
};

// ---------------------------------------------------------------------------
// GRU body (r5-proven MFMA version, TC steps). One block = one batch element.
// 8 waves; wave w owns h-cols [32w,32w+32). U register-resident as B-frags.
// outp layout: outp[(b*os + obase + tl)*HID + col].
// ---------------------------------------------------------------------------
__device__ __forceinline__ void gru_body(
    char* smem, const float* __restrict__ xp, const float* __restrict__ Bfrag,
    const float* __restrict__ bb, const int* __restrict__ batch,
    float* __restrict__ outp, int os, int obase,
    float* __restrict__ hfinal, float* __restrict__ hstate, int t0, int b)
{
    _Float16 (*hbuf)[HID] = (_Float16 (*)[HID])smem;

    const int T  = threadIdx.x;
    const int w  = T >> 6;
    const int l  = T & 63;
    const int g  = l >> 4;
    const int i  = l & 15;
    const int g1 = g & 1;
    const int c  = 32 * w + i + 16 * g1;

    f16x8 Bf[6][8];
    {
        const int cts[6] = {2 * w, 16 + 2 * w, 32 + 2 * w,
                            2 * w + 1, 17 + 2 * w, 33 + 2 * w};
#pragma unroll
        for (int ci = 0; ci < 6; ++ci)
#pragma unroll
            for (int kt = 0; kt < 8; ++kt) {
                float4 v = *(const float4*)(Bfrag + ((size_t)(cts[ci] * 8 + kt) * 64 + l) * 4);
                Bf[ci][kt] = __builtin_bit_cast(f16x8, v);
            }
    }

    const float bh = bb[GATE + 2 * HID + c];

    float hprev = (t0 == 0) ? 0.0f : hstate[b * HID + c];
    if (l < 32) hbuf[0][32 * w + l] = (_Float16)hprev;
    __syncthreads();

    for (int tl = 0; tl < TC; ++tl) {
        const float* xrow = xp + ((size_t)b * TC + tl) * GATE;
        const float xz = xrow[c];
        const float xr = xrow[HID + c];
        const float xh = xrow[2 * HID + c];
        const int   mf = batch[((size_t)b * SEQ + t0 + tl) * FEAT + (FEAT - 1)];

        const _Float16* rd = hbuf[tl & 1];

        f32x4 az0 = {0.f, 0.f, 0.f, 0.f}, ar0 = az0, ah0 = az0;
        f32x4 az1 = az0, ar1 = az0, ah1 = az0;
#pragma unroll
        for (int kt = 0; kt < 8; ++kt) {
            const f16x8 a = *(const f16x8*)(rd + kt * 32 + g * 8);
            az0 = __builtin_amdgcn_mfma_f32_16x16x32_f16(a, Bf[0][kt], az0, 0, 0, 0);
            ar0 = __builtin_amdgcn_mfma_f32_16x16x32_f16(a, Bf[1][kt], ar0, 0, 0, 0);
            ah0 = __builtin_amdgcn_mfma_f32_16x16x32_f16(a, Bf[2][kt], ah0, 0, 0, 0);
            az1 = __builtin_amdgcn_mfma_f32_16x16x32_f16(a, Bf[3][kt], az1, 0, 0, 0);
            ar1 = __builtin_amdgcn_mfma_f32_16x16x32_f16(a, Bf[4][kt], ar1, 0, 0, 0);
            ah1 = __builtin_amdgcn_mfma_f32_16x16x32_f16(a, Bf[5][kt], ah1, 0, 0, 0);
        }

        const float az = g1 ? az1[0] : az0[0];
        const float ar = g1 ? ar1[0] : ar0[0];
        const float ah = g1 ? ah1[0] : ah0[0];

        const float z  = sigmoidf_(xz + az);
        const float r  = sigmoidf_(xr + ar);
        const float hh = tanhf_(xh + r * (ah + bh));
        float hn = z * hprev + (1.0f - z) * hh;
        hn = (mf != -1) ? hn : hprev;
        hprev = hn;

        if (l < 32) {
            outp[((size_t)b * os + obase + tl) * HID + 32 * w + l] = hn;
            hbuf[(tl & 1) ^ 1][32 * w + l] = (_Float16)hn;
        }
        __syncthreads();
    }

    if (l < 32) {
        hstate[b * HID + 32 * w + l] = hprev;
        if (hfinal) hfinal[b * HID + 32 * w + l] = hprev;
    }
}

// ---------------------------------------------------------------------------
// GEMM body: xp[r,n] = bias(n) + sum_k Yc[r,k] * W[k,n]; Yc chunk-local
// [BATCH*TC rows][HID]. 512 threads, 64x128 tile, BK=16, 4x4 micro-tile.
// e = tile index: bx = e/6 (M), by = e%6 (N).
// ---------------------------------------------------------------------------
__device__ __forceinline__ void gemm_body(
    char* smem, const float* __restrict__ Yc, const float* __restrict__ W,
    const float* __restrict__ bb, float* __restrict__ xpout, int e)
{
    float (*As)[68]  = (float (*)[68])smem;                    // [16][68]
    float (*Bs)[128] = (float (*)[128])(smem + 16 * 68 * 4);   // [16][128]

    const int bx = e / 6, by = e % 6;
    const int m0 = bx * 64, n0 = by * 128;
    const int tid = threadIdx.x;
    const int lrA = tid >> 3, lcA = (tid & 7) * 2;
    const int lrB = tid >> 5, lcB = (tid & 31) * 4;
    const int ty = tid >> 5, tx = tid & 31;

    float acc[4][4] = {};

    for (int k0 = 0; k0 < HID; k0 += 16) {
        float2 av = *(const float2*)(Yc + (size_t)(m0 + lrA) * HID + k0 + lcA);
        As[lcA][lrA] = av.x; As[lcA + 1][lrA] = av.y;
        float4 bv = *(const float4*)(W + (size_t)(k0 + lrB) * GATE + n0 + lcB);
        *(float4*)&Bs[lrB][lcB] = bv;
        __syncthreads();
#pragma unroll
        for (int k = 0; k < 16; ++k) {
            float4 a  = *(const float4*)&As[k][ty * 4];
            float4 bq = *(const float4*)&Bs[k][tx * 4];
            float a_[4] = {a.x, a.y, a.z, a.w};
            float b_[4] = {bq.x, bq.y, bq.z, bq.w};
#pragma unroll
            for (int ii = 0; ii < 4; ++ii)
#pragma unroll
                for (int jj = 0; jj < 4; ++jj)
                    acc[ii][jj] += a_[ii] * b_[jj];
        }
        __syncthreads();
    }

#pragma unroll
    for (int ii = 0; ii < 4; ++ii) {
        const int row = m0 + ty * 4 + ii;
#pragma unroll
        for (int jj = 0; jj < 4; ++jj) {
            const int n = n0 + tx * 4 + jj;
            xpout[(size_t)row * GATE + n] =
                acc[ii][jj] + bb[n] + ((n < 2 * HID) ? bb[GATE + n] : 0.0f);
        }
    }
}

// ---------------------------------------------------------------------------
// Layer-0 projection body: one block per batch element, 512 threads.
// ---------------------------------------------------------------------------
__device__ __forceinline__ void xp0_body(
    const int* __restrict__ batch, const float* __restrict__ W0,
    const float* __restrict__ bb, float* __restrict__ xpout, int t0, int b)
{
    const int tid = threadIdx.x;
    for (int tl = 0; tl < TC; ++tl) {
        const int* xr = batch + ((size_t)b * SEQ + t0 + tl) * FEAT;
        float xf[FEAT];
#pragma unroll
        for (int f = 0; f < FEAT; ++f) xf[f] = (float)xr[f];
        for (int cc = tid; cc < GATE; cc += NT) {
            float acc = bb[cc] + ((cc < 2 * HID) ? bb[GATE + cc] : 0.0f);
#pragma unroll
            for (int f = 0; f < FEAT; ++f)
                acc += xf[f] * W0[f * GATE + cc];
            xpout[((size_t)b * TC + tl) * GATE + cc] = acc;
        }
    }
}

// ---------------------------------------------------------------------------
// Fused pipeline kernel. Launch d executes:
//   blocks   0- 63 : gru layer0, chunk d
//   blocks  64-127 : gru layer1, chunk d-2
//   blocks 128-191 : gru layer2, chunk d-4
//   blocks 192-255 : xp0 projection, chunk d+1
//   blocks 256-639 : gemm layer1 xp, chunk d-1   (consumes y0 from launch d-1)
//   blocks 640-1023: gemm layer2 xp, chunk d-3   (consumes y1 from launch d-1)
// All roles in one launch are mutually independent; rings are depth-2
// (parity by chunk index), writer and reader always in different launches.
// ---------------------------------------------------------------------------
__global__ __launch_bounds__(NT, 1) void k_fused(Params P, int d)
{
    __shared__ __align__(16) char smem[16 * 68 * 4 + 16 * 128 * 4];
    const int bid = blockIdx.x;

    if (bid < 64) {
        const int c = d;
        if (c >= 0 && c <= LASTC)
            gru_body(smem, (c & 1) ? P.xp0b : P.xp0a, P.Bf0, P.b0, P.batch,
                     (c & 1) ? P.y0b : P.y0a, TC, 0, nullptr, P.h0, c * TC, bid);
    } else if (bid < 128) {
        const int c = d - 2;
        if (c >= 0 && c <= LASTC)
            gru_body(smem, (c & 1) ? P.xp1b : P.xp1a, P.Bf1, P.b1, P.batch,
                     (c & 1) ? P.y1b : P.y1a, TC, 0, nullptr, P.h1, c * TC, bid - 64);
    } else if (bid < 192) {
        const int c = d - 4;
        if (c >= 0 && c <= LASTC)
            gru_body(smem, (c & 1) ? P.xp2b : P.xp2a, P.Bf2, P.b2, P.batch,
                     P.out, SEQ, c * TC, (c == LASTC) ? P.hfin : nullptr,
                     P.h2, c * TC, bid - 128);
    } else if (bid < 256) {
        const int c = d + 1;
        if (c >= 0 && c <= LASTC)
            xp0_body(P.batch, P.W0, P.b0, (c & 1) ? P.xp0b : P.xp0a,
                     c * TC, bid - 192);
    } else if (bid < 640) {
        const int c = d - 1;
        if (c >= 0 && c <= LASTC)
            gemm_body(smem, (c & 1) ? P.y0b : P.y0a, P.W1, P.b1,
                      (c & 1) ? P.xp1b : P.xp1a, bid - 256);
    } else {
        const int c = d - 3;
        if (c >= 0 && c <= LASTC)
            gemm_body(smem, (c & 1) ? P.y1b : P.y1a, P.W2, P.b2,
                      (c & 1) ? P.xp2b : P.xp2a, bid - 640);
    }
}

// ---------------------------------------------------------------------------
extern "C" void kernel_launch(void* const* d_in, const int* in_sizes, int n_in,
                              void* d_out, int out_size, void* d_ws, size_t ws_size,
                              hipStream_t stream)
{
    const int*   batch = (const int*)d_in[0];
    const float* W0 = (const float*)d_in[1];
    const float* U0 = (const float*)d_in[2];
    const float* b0 = (const float*)d_in[3];
    const float* W1 = (const float*)d_in[4];
    const float* U1 = (const float*)d_in[5];
    const float* b1 = (const float*)d_in[6];
    const float* W2 = (const float*)d_in[7];
    const float* U2 = (const float*)d_in[8];
    const float* b2 = (const float*)d_in[9];

    float* out  = (float*)d_out;
    float* hfin = out + (size_t)BATCH * SEQ * HID;

    const size_t XPC = (size_t)BATCH * TC * GATE;   // xp chunk floats
    const size_t YC  = (size_t)BATCH * TC * HID;    // y chunk floats
    const size_t BFC = (size_t)48 * 8 * 64 * 4;     // B-frag floats

    float* p = (float*)d_ws;
    float* xp0a = p; p += XPC;  float* xp0b = p; p += XPC;
    float* xp1a = p; p += XPC;  float* xp1b = p; p += XPC;
    float* xp2a = p; p += XPC;  float* xp2b = p; p += XPC;
    float* y0a  = p; p += YC;   float* y0b  = p; p += YC;
    float* y1a  = p; p += YC;   float* y1b  = p; p += YC;
    float* h0   = p; p += (size_t)BATCH * HID;
    float* h1   = p; p += (size_t)BATCH * HID;
    float* h2   = p; p += (size_t)BATCH * HID;
    float* Bf0  = p; p += BFC;
    float* Bf1  = p; p += BFC;
    float* Bf2  = p; p += BFC;

    dim3 gpack(48 * 8 * 64 / 256), bpack(256);
    k_packB<<<gpack, bpack, 0, stream>>>(U0, Bf0);
    k_packB<<<gpack, bpack, 0, stream>>>(U1, Bf1);
    k_packB<<<gpack, bpack, 0, stream>>>(U2, Bf2);

    Params P;
    P.batch = batch;
    P.W0 = W0; P.b0 = b0; P.W1 = W1; P.b1 = b1; P.W2 = W2; P.b2 = b2;
    P.Bf0 = Bf0; P.Bf1 = Bf1; P.Bf2 = Bf2;
    P.xp0a = xp0a; P.xp0b = xp0b; P.xp1a = xp1a; P.xp1b = xp1b;
    P.xp2a = xp2a; P.xp2b = xp2b;
    P.y0a = y0a; P.y0b = y0b; P.y1a = y1a; P.y1b = y1b;
    P.h0 = h0; P.h1 = h1; P.h2 = h2;
    P.out = out; P.hfin = hfin;

    for (int d = -1; d <= LASTC + 4; ++d)
        k_fused<<<dim3(1024), dim3(NT), 0, stream>>>(P, d);
}